// Round 1
// baseline (57.739 us; speedup 1.0000x reference)
//
#include <hip/hip_runtime.h>

#define B_    1024
#define NIN_  128
#define NOUT_ 128
#define N_    512
#define EPS_  1e-5f

// Stage 1: masked reduce over n  +  fused 128x128 linear
// grid = B_, block = 256
__global__ __launch_bounds__(256) void k1_maskreduce_linear(
    const int* __restrict__ A, const float* __restrict__ x,
    const float* __restrict__ W, const float* __restrict__ bias,
    const int* __restrict__ dil_p, float* __restrict__ h,
    float* __restrict__ outA)
{
    __shared__ float m[N_];
    __shared__ float s[NIN_];
    const int b = blockIdx.x;
    const int t = threadIdx.x;
    const int dil = *dil_p;

    // Load A row, build mask in LDS, and emit output 0 (A as float)
    const int* Arow = A + (size_t)b * N_;
    float* oA = outA + (size_t)b * N_;
    for (int n = t; n < N_; n += 256) {
        int a = Arow[n];
        m[n] = (a == dil || a == -1) ? 1.0f : 0.0f;
        oA[n] = (float)a;
    }
    __syncthreads();

    const int wave = t >> 6;
    const int lane = t & 63;

    // Each lane's 8 mask values are channel-invariant: hoist to registers.
    float mm[8];
    #pragma unroll
    for (int j = 0; j < 8; ++j) mm[j] = m[lane * 8 + j];

    // 4 waves x 32 channels; per channel: 2 coalesced float4 loads + reduce
    for (int i = wave; i < NIN_; i += 4) {
        const float4* xp = (const float4*)(x + ((size_t)b * NIN_ + i) * N_ + lane * 8);
        float4 v0 = xp[0];
        float4 v1 = xp[1];
        float acc = v0.x * mm[0] + v0.y * mm[1] + v0.z * mm[2] + v0.w * mm[3]
                  + v1.x * mm[4] + v1.y * mm[5] + v1.z * mm[6] + v1.w * mm[7];
        #pragma unroll
        for (int off = 32; off > 0; off >>= 1)
            acc += __shfl_xor(acc, off, 64);
        if (lane == 0) s[i] = acc;
    }
    __syncthreads();

    // h[b,o] = bias[o] + sum_i W[o,i] * s[i]   (threads 0..127; W L2-resident)
    if (t < NOUT_) {
        const float* Wr = W + (size_t)t * NIN_;
        float acc = bias[t];
        #pragma unroll 8
        for (int i = 0; i < NIN_; ++i) acc += Wr[i] * s[i];
        h[(size_t)b * NOUT_ + t] = acc;
    }
}

// Stage 2: per-output-channel batch stats -> scale/shift
// grid = NOUT_, block = 256
__global__ __launch_bounds__(256) void k2_stats(
    const float* __restrict__ h, const float* __restrict__ gamma,
    const float* __restrict__ beta, float* __restrict__ ss)
{
    const int o = blockIdx.x;
    const int t = threadIdx.x;
    float sum = 0.f, sq = 0.f;
    for (int b = t; b < B_; b += 256) {
        float v = h[(size_t)b * NOUT_ + o];
        sum += v;
        sq  += v * v;
    }
    #pragma unroll
    for (int off = 32; off > 0; off >>= 1) {
        sum += __shfl_xor(sum, off, 64);
        sq  += __shfl_xor(sq,  off, 64);
    }
    __shared__ float red[8];
    const int wave = t >> 6, lane = t & 63;
    if (lane == 0) { red[wave] = sum; red[4 + wave] = sq; }
    __syncthreads();
    if (t == 0) {
        float S = red[0] + red[1] + red[2] + red[3];
        float Q = red[4] + red[5] + red[6] + red[7];
        float mean = S * (1.0f / B_);
        float var  = Q * (1.0f / B_) - mean * mean;   // biased, training mode
        float rstd = rsqrtf(var + EPS_);
        float sc = gamma[o] * rstd;
        ss[o]         = sc;
        ss[NOUT_ + o] = beta[o] - mean * sc;
    }
}

// Stage 3: normalize + ReLU -> output 1
// grid = B_*NOUT_/256, block = 256
__global__ __launch_bounds__(256) void k3_norm(
    const float* __restrict__ h, const float* __restrict__ ss,
    float* __restrict__ outF)
{
    const int idx = blockIdx.x * 256 + threadIdx.x;
    const int o = idx & (NOUT_ - 1);
    float v = fmaf(h[idx], ss[o], ss[NOUT_ + o]);
    outF[idx] = fmaxf(v, 0.0f);
}

extern "C" void kernel_launch(void* const* d_in, const int* in_sizes, int n_in,
                              void* d_out, int out_size, void* d_ws, size_t ws_size,
                              hipStream_t stream) {
    const int*   A     = (const int*)d_in[0];
    const float* x     = (const float*)d_in[1];
    const float* W     = (const float*)d_in[2];
    const float* bias  = (const float*)d_in[3];
    const float* gamma = (const float*)d_in[4];
    const float* beta  = (const float*)d_in[5];
    const int*   dil   = (const int*)d_in[6];

    float* out  = (float*)d_out;
    float* outA = out;                       // B*1*N = 524288 floats (A passthrough)
    float* outF = out + (size_t)B_ * N_;     // B*NOUT = 131072 floats (features)

    float* h  = (float*)d_ws;                // B*NOUT floats = 512 KB
    float* ss = h + (size_t)B_ * NOUT_;      // 2*NOUT floats

    k1_maskreduce_linear<<<B_, 256, 0, stream>>>(A, x, W, bias, dil, h, outA);
    k2_stats<<<NOUT_, 256, 0, stream>>>(h, gamma, beta, ss);
    k3_norm<<<(B_ * NOUT_) / 256, 256, 0, stream>>>(h, ss, outF);
}

// Round 2
// 57.237 us; speedup vs baseline: 1.0088x; 1.0088x over previous
//
#include <hip/hip_runtime.h>

#define B_    1024
#define NIN_  128
#define NOUT_ 128
#define N_    512
#define EPS_  1e-5f

// Stage 1: masked reduce over n  +  fused 128x128 linear
// grid = B_, block = 512 (8 waves -> 4 blocks/CU = 32 waves/CU, full occupancy)
__global__ __launch_bounds__(512) void k1_maskreduce_linear(
    const int* __restrict__ A, const float* __restrict__ x,
    const float* __restrict__ W, const float* __restrict__ bias,
    const int* __restrict__ dil_p, float* __restrict__ h,
    float* __restrict__ outA)
{
    __shared__ float m[N_];
    __shared__ float s[NIN_];
    const int b = blockIdx.x;
    const int t = threadIdx.x;
    const int dil = *dil_p;

    // Load A row, build mask in LDS, and emit output 0 (A as float)
    const int* Arow = A + (size_t)b * N_;
    float* oA = outA + (size_t)b * N_;
    {
        int n = t;               // 512 threads, N_=512: one element each
        int a = Arow[n];
        m[n] = (a == dil || a == -1) ? 1.0f : 0.0f;
        oA[n] = (float)a;
    }
    __syncthreads();

    const int wave = t >> 6;
    const int lane = t & 63;

    // Per-lane mask registers: lane l covers n in [4l,4l+4) and [256+4l,256+4l+4)
    float mA[4], mB[4];
    #pragma unroll
    for (int j = 0; j < 4; ++j) {
        mA[j] = m[lane * 4 + j];
        mB[j] = m[256 + lane * 4 + j];
    }

    // 8 waves x 16 channels; per channel: two fully-contiguous 1KB wave loads
    for (int i = wave; i < NIN_; i += 8) {
        const float* row = x + ((size_t)b * NIN_ + i) * N_;
        float4 v0 = *(const float4*)(row + lane * 4);
        float4 v1 = *(const float4*)(row + 256 + lane * 4);
        float acc = v0.x * mA[0] + v0.y * mA[1] + v0.z * mA[2] + v0.w * mA[3]
                  + v1.x * mB[0] + v1.y * mB[1] + v1.z * mB[2] + v1.w * mB[3];
        #pragma unroll
        for (int off = 32; off > 0; off >>= 1)
            acc += __shfl_xor(acc, off, 64);
        if (lane == 0) s[i] = acc;
    }
    __syncthreads();

    // h[b,o] = bias[o] + sum_i W[o,i] * s[i]   (threads 0..127; W L2-resident)
    if (t < NOUT_) {
        const float* Wr = W + (size_t)t * NIN_;
        float acc = bias[t];
        #pragma unroll 8
        for (int i = 0; i < NIN_; ++i) acc += Wr[i] * s[i];
        h[(size_t)b * NOUT_ + t] = acc;
    }
}

// Stage 2: per-output-channel batch stats -> scale/shift
// grid = NOUT_, block = 256
__global__ __launch_bounds__(256) void k2_stats(
    const float* __restrict__ h, const float* __restrict__ gamma,
    const float* __restrict__ beta, float* __restrict__ ss)
{
    const int o = blockIdx.x;
    const int t = threadIdx.x;
    float sum = 0.f, sq = 0.f;
    for (int b = t; b < B_; b += 256) {
        float v = h[(size_t)b * NOUT_ + o];
        sum += v;
        sq  += v * v;
    }
    #pragma unroll
    for (int off = 32; off > 0; off >>= 1) {
        sum += __shfl_xor(sum, off, 64);
        sq  += __shfl_xor(sq,  off, 64);
    }
    __shared__ float red[8];
    const int wave = t >> 6, lane = t & 63;
    if (lane == 0) { red[wave] = sum; red[4 + wave] = sq; }
    __syncthreads();
    if (t == 0) {
        float S = red[0] + red[1] + red[2] + red[3];
        float Q = red[4] + red[5] + red[6] + red[7];
        float mean = S * (1.0f / B_);
        float var  = Q * (1.0f / B_) - mean * mean;   // biased, training mode
        float rstd = rsqrtf(var + EPS_);
        float sc = gamma[o] * rstd;
        ss[o]         = sc;
        ss[NOUT_ + o] = beta[o] - mean * sc;
    }
}

// Stage 3: normalize + ReLU -> output 1
// grid = B_*NOUT_/256, block = 256
__global__ __launch_bounds__(256) void k3_norm(
    const float* __restrict__ h, const float* __restrict__ ss,
    float* __restrict__ outF)
{
    const int idx = blockIdx.x * 256 + threadIdx.x;
    const int o = idx & (NOUT_ - 1);
    float v = fmaf(h[idx], ss[o], ss[NOUT_ + o]);
    outF[idx] = fmaxf(v, 0.0f);
}

extern "C" void kernel_launch(void* const* d_in, const int* in_sizes, int n_in,
                              void* d_out, int out_size, void* d_ws, size_t ws_size,
                              hipStream_t stream) {
    const int*   A     = (const int*)d_in[0];
    const float* x     = (const float*)d_in[1];
    const float* W     = (const float*)d_in[2];
    const float* bias  = (const float*)d_in[3];
    const float* gamma = (const float*)d_in[4];
    const float* beta  = (const float*)d_in[5];
    const int*   dil   = (const int*)d_in[6];

    float* out  = (float*)d_out;
    float* outA = out;                       // B*1*N = 524288 floats (A passthrough)
    float* outF = out + (size_t)B_ * N_;     // B*NOUT = 131072 floats (features)

    float* h  = (float*)d_ws;                // B*NOUT floats = 512 KB
    float* ss = h + (size_t)B_ * NOUT_;      // 2*NOUT floats

    k1_maskreduce_linear<<<B_, 512, 0, stream>>>(A, x, W, bias, dil, h, outA);
    k2_stats<<<NOUT_, 256, 0, stream>>>(h, gamma, beta, ss);
    k3_norm<<<(B_ * NOUT_) / 256, 256, 0, stream>>>(h, ss, outF);
}